// Round 4
// baseline (221.404 us; speedup 1.0000x reference)
//
#include <hip/hip_runtime.h>
#include <stdint.h>
#include <math.h>

#define NH 32
#define NH2 8
#define DD 128
#define KSEL 128
#define GG 4
#define S2MASK 8191   // S2=8192
#define KVELTS (8192 * NH2 * DD)   // 8,388,608 elements per tensor

typedef _Float16 h8   __attribute__((ext_vector_type(8)));
typedef _Float16 h2t  __attribute__((ext_vector_type(2)));
typedef __fp16   hp2  __attribute__((ext_vector_type(2)));
typedef float    f32x4 __attribute__((ext_vector_type(4)));

// exact fp32->fp16 pack (inputs are harness-upcast fp16, so RTZ is lossless)
static __device__ __forceinline__ h8 cvt8(float4 a, float4 b) {
  union { h8 v; hp2 p[4]; } u;
  u.p[0] = __builtin_amdgcn_cvt_pkrtz(a.x, a.y);
  u.p[1] = __builtin_amdgcn_cvt_pkrtz(a.z, a.w);
  u.p[2] = __builtin_amdgcn_cvt_pkrtz(b.x, b.y);
  u.p[3] = __builtin_amdgcn_cvt_pkrtz(b.z, b.w);
  return u.v;
}

// ---- pre-pass: K,V fp32 -> fp16 in workspace (exact; halves gather bytes) ----
__global__ __launch_bounds__(256) void convert_kv(
    const float4* __restrict__ kf, const float4* __restrict__ vf,
    ushort4* __restrict__ kh, ushort4* __restrict__ vh, int n4) {
  int i = blockIdx.x * blockDim.x + threadIdx.x;
  const int stride = gridDim.x * blockDim.x;
  union { ushort4 u; hp2 p[2]; } ua;
  for (; i < n4; i += stride) {
    float4 a = kf[i];
    ua.p[0] = __builtin_amdgcn_cvt_pkrtz(a.x, a.y);
    ua.p[1] = __builtin_amdgcn_cvt_pkrtz(a.z, a.w);
    kh[i] = ua.u;
    float4 b = vf[i];
    ua.p[0] = __builtin_amdgcn_cvt_pkrtz(b.x, b.y);
    ua.p[1] = __builtin_amdgcn_cvt_pkrtz(b.z, b.w);
    vh[i] = ua.u;
  }
}

// ---- main kernel, fp16 K/V from workspace; NO barriers (all wave-private) ----
__global__ __launch_bounds__(256) void sparse_attn_f16(
    const float* __restrict__ q, const _Float16* __restrict__ kh,
    const _Float16* __restrict__ vh, const int* __restrict__ idx,
    float* __restrict__ out) {
  __shared__ int sOff[4][KSEL];                      // element offset s2*NH2*DD
  __shared__ __align__(16) float sP[4][KSEL][GG];    // scores -> P, [key][g]

  const int tid = threadIdx.x;
  const int w = tid >> 6;
  const int lane = tid & 63;
  const int h2 = blockIdx.x & 7;                 // XCD-pinned KV head
  const int s1 = ((blockIdx.x >> 3) << 2) + w;   // query position

  const int* ip = idx + (s1 * NH2 + h2) * KSEL;
  sOff[w][lane]      = (ip[lane]      & S2MASK) * (NH2 * DD);
  sOff[w][lane + 64] = (ip[lane + 64] & S2MASK) * (NH2 * DD);

  // MFMA 16x16x32_f16 lane roles:
  //   A: row m = lane&15 (query, m<4 valid, rest zero), k = 8*(lane>>4)+i
  //   B: col    = lane&15 (key-in-tile),                k = 8*(lane>>4)+i
  //   C: col = lane&15 (key), row = 4*(lane>>4)+r -> lanes 0..15 hold all 4 g
  const int m  = lane & 15;
  const int kg = lane >> 4;

  h8 aq[4];
#pragma unroll
  for (int t = 0; t < 4; ++t)
#pragma unroll
    for (int i = 0; i < 8; ++i) aq[t][i] = (_Float16)0;
  if (m < GG) {
    const float* qp = q + (s1 * NH + h2 * GG + m) * DD + kg * 8;
#pragma unroll
    for (int t = 0; t < 4; ++t) {
      float4 f0 = *(const float4*)(qp + 32 * t);
      float4 f1 = *(const float4*)(qp + 32 * t + 4);
      aq[t] = cvt8(f0, f1);
    }
  }

  const float scale = 0.08838834764831845f;  // 1/sqrt(128)

  // ---- Phase 1: scores = Q.K^T via MFMA; fp16 K rows feed B natively ----
#pragma unroll 2
  for (int nt = 0; nt < 8; ++nt) {
    const _Float16* kp = kh + sOff[w][nt * 16 + m] + h2 * DD + kg * 8;
    f32x4 acc = {0.f, 0.f, 0.f, 0.f};
#pragma unroll
    for (int t = 0; t < 4; ++t) {
      h8 bk = *(const h8*)(kp + 32 * t);
      acc = __builtin_amdgcn_mfma_f32_16x16x32_f16(aq[t], bk, acc, 0, 0, 0);
    }
    if (lane < 16) {
      float4 sc = make_float4(acc[0] * scale, acc[1] * scale,
                              acc[2] * scale, acc[3] * scale);
      *(float4*)&sP[w][nt * 16 + lane][0] = sc;
    }
  }

  // ---- V chunk-0 prefetch: latency hides under the softmax ----
  const _Float16* vb = vh + h2 * DD + lane * 2;
  h2t vreg[2][16];
#pragma unroll
  for (int j = 0; j < 16; ++j)
    vreg[0][j] = *(const h2t*)(vb + sOff[w][j]);

  // ---- Phase 2: softmax, all 64 lanes (lane owns keys {lane, lane+64}) ----
  {
    float4 p0 = *(const float4*)&sP[w][lane][0];
    float4 p1 = *(const float4*)&sP[w][lane + 64][0];
    float4 mx = make_float4(fmaxf(p0.x, p1.x), fmaxf(p0.y, p1.y),
                            fmaxf(p0.z, p1.z), fmaxf(p0.w, p1.w));
#pragma unroll
    for (int off = 1; off < 64; off <<= 1) {
      mx.x = fmaxf(mx.x, __shfl_xor(mx.x, off));
      mx.y = fmaxf(mx.y, __shfl_xor(mx.y, off));
      mx.z = fmaxf(mx.z, __shfl_xor(mx.z, off));
      mx.w = fmaxf(mx.w, __shfl_xor(mx.w, off));
    }
    float4 e0 = make_float4(__expf(p0.x - mx.x), __expf(p0.y - mx.y),
                            __expf(p0.z - mx.z), __expf(p0.w - mx.w));
    float4 e1 = make_float4(__expf(p1.x - mx.x), __expf(p1.y - mx.y),
                            __expf(p1.z - mx.z), __expf(p1.w - mx.w));
    float4 sm = make_float4(e0.x + e1.x, e0.y + e1.y, e0.z + e1.z, e0.w + e1.w);
#pragma unroll
    for (int off = 1; off < 64; off <<= 1) {
      sm.x += __shfl_xor(sm.x, off);
      sm.y += __shfl_xor(sm.y, off);
      sm.z += __shfl_xor(sm.z, off);
      sm.w += __shfl_xor(sm.w, off);
    }
    float4 inv = make_float4(1.f / fmaxf(sm.x, 1e-30f), 1.f / fmaxf(sm.y, 1e-30f),
                             1.f / fmaxf(sm.z, 1e-30f), 1.f / fmaxf(sm.w, 1e-30f));
    *(float4*)&sP[w][lane][0] =
        make_float4(e0.x * inv.x, e0.y * inv.y, e0.z * inv.z, e0.w * inv.w);
    *(float4*)&sP[w][lane + 64][0] =
        make_float4(e1.x * inv.x, e1.y * inv.y, e1.z * inv.z, e1.w * inv.w);
  }

  // ---- Phase 3: O = P . V ; register double-buffered chunks of 16 keys ----
  float a00 = 0.f, a01 = 0.f, a10 = 0.f, a11 = 0.f;
  float a20 = 0.f, a21 = 0.f, a30 = 0.f, a31 = 0.f;
#pragma unroll
  for (int ch = 0; ch < 8; ++ch) {
    const int cur = ch & 1, nxt = cur ^ 1;
    if (ch < 7) {
#pragma unroll
      for (int j = 0; j < 16; ++j)
        vreg[nxt][j] = *(const h2t*)(vb + sOff[w][(ch + 1) * 16 + j]);
    }
#pragma unroll
    for (int j = 0; j < 16; ++j) {
      const float4 p = *(const float4*)&sP[w][ch * 16 + j][0];
      const float vx = (float)vreg[cur][j][0];
      const float vy = (float)vreg[cur][j][1];
      a00 = fmaf(p.x, vx, a00); a01 = fmaf(p.x, vy, a01);
      a10 = fmaf(p.y, vx, a10); a11 = fmaf(p.y, vy, a11);
      a20 = fmaf(p.z, vx, a20); a21 = fmaf(p.z, vy, a21);
      a30 = fmaf(p.w, vx, a30); a31 = fmaf(p.w, vy, a31);
    }
  }

  float* op = out + (s1 * NH + h2 * GG) * DD + lane * 2;
  *(float2*)(op + 0 * DD) = make_float2(a00, a01);
  *(float2*)(op + 1 * DD) = make_float2(a10, a11);
  *(float2*)(op + 2 * DD) = make_float2(a20, a21);
  *(float2*)(op + 3 * DD) = make_float2(a30, a31);
}

// ---- fallback: fp32 K/V direct, used when workspace too small ----
__global__ __launch_bounds__(256) void sparse_attn_f32(
    const float* __restrict__ q, const float* __restrict__ k,
    const float* __restrict__ v, const int* __restrict__ idx,
    float* __restrict__ out) {
  __shared__ int sIdx[4][KSEL];
  __shared__ __align__(16) float sP[4][KSEL][GG];

  const int tid = threadIdx.x;
  const int w = tid >> 6;
  const int lane = tid & 63;
  const int h2 = blockIdx.x & 7;
  const int s1 = ((blockIdx.x >> 3) << 2) + w;

  const int* ip = idx + (s1 * NH2 + h2) * KSEL;
  sIdx[w][lane]      = ip[lane] & S2MASK;
  sIdx[w][lane + 64] = ip[lane + 64] & S2MASK;

  const int m  = lane & 15;
  const int kg = lane >> 4;

  h8 aq[4];
#pragma unroll
  for (int t = 0; t < 4; ++t)
#pragma unroll
    for (int i = 0; i < 8; ++i) aq[t][i] = (_Float16)0;
  if (m < GG) {
    const float* qp = q + (s1 * NH + h2 * GG + m) * DD + kg * 8;
#pragma unroll
    for (int t = 0; t < 4; ++t) {
      float4 f0 = *(const float4*)(qp + 32 * t);
      float4 f1 = *(const float4*)(qp + 32 * t + 4);
      aq[t] = cvt8(f0, f1);
    }
  }
  __syncthreads();

  const float scale = 0.08838834764831845f;
#pragma unroll 2
  for (int nt = 0; nt < 8; ++nt) {
    const int s2 = sIdx[w][nt * 16 + m];
    const float* kp = k + (s2 * NH2 + h2) * DD + kg * 8;
    f32x4 acc = {0.f, 0.f, 0.f, 0.f};
#pragma unroll
    for (int t = 0; t < 4; ++t) {
      float4 f0 = *(const float4*)(kp + 32 * t);
      float4 f1 = *(const float4*)(kp + 32 * t + 4);
      acc = __builtin_amdgcn_mfma_f32_16x16x32_f16(aq[t], cvt8(f0, f1), acc, 0, 0, 0);
    }
    if (lane < 16) {
      float4 sc = make_float4(acc[0] * scale, acc[1] * scale,
                              acc[2] * scale, acc[3] * scale);
      *(float4*)&sP[w][nt * 16 + lane][0] = sc;
    }
  }
  __syncthreads();

  {
    float4 p0 = *(const float4*)&sP[w][lane][0];
    float4 p1 = *(const float4*)&sP[w][lane + 64][0];
    float4 mx = make_float4(fmaxf(p0.x, p1.x), fmaxf(p0.y, p1.y),
                            fmaxf(p0.z, p1.z), fmaxf(p0.w, p1.w));
#pragma unroll
    for (int off = 1; off < 64; off <<= 1) {
      mx.x = fmaxf(mx.x, __shfl_xor(mx.x, off));
      mx.y = fmaxf(mx.y, __shfl_xor(mx.y, off));
      mx.z = fmaxf(mx.z, __shfl_xor(mx.z, off));
      mx.w = fmaxf(mx.w, __shfl_xor(mx.w, off));
    }
    float4 e0 = make_float4(__expf(p0.x - mx.x), __expf(p0.y - mx.y),
                            __expf(p0.z - mx.z), __expf(p0.w - mx.w));
    float4 e1 = make_float4(__expf(p1.x - mx.x), __expf(p1.y - mx.y),
                            __expf(p1.z - mx.z), __expf(p1.w - mx.w));
    float4 sm = make_float4(e0.x + e1.x, e0.y + e1.y, e0.z + e1.z, e0.w + e1.w);
#pragma unroll
    for (int off = 1; off < 64; off <<= 1) {
      sm.x += __shfl_xor(sm.x, off);
      sm.y += __shfl_xor(sm.y, off);
      sm.z += __shfl_xor(sm.z, off);
      sm.w += __shfl_xor(sm.w, off);
    }
    float4 inv = make_float4(1.f / fmaxf(sm.x, 1e-30f), 1.f / fmaxf(sm.y, 1e-30f),
                             1.f / fmaxf(sm.z, 1e-30f), 1.f / fmaxf(sm.w, 1e-30f));
    *(float4*)&sP[w][lane][0] =
        make_float4(e0.x * inv.x, e0.y * inv.y, e0.z * inv.z, e0.w * inv.w);
    *(float4*)&sP[w][lane + 64][0] =
        make_float4(e1.x * inv.x, e1.y * inv.y, e1.z * inv.z, e1.w * inv.w);
  }
  __syncthreads();

  float a00 = 0.f, a01 = 0.f, a10 = 0.f, a11 = 0.f;
  float a20 = 0.f, a21 = 0.f, a30 = 0.f, a31 = 0.f;
  const float* vb = v + h2 * DD + lane * 2;
#pragma unroll 8
  for (int j = 0; j < KSEL; ++j) {
    const int s2 = sIdx[w][j];
    const float2 vv = *(const float2*)(vb + (size_t)s2 * (NH2 * DD));
    const float4 p = *(const float4*)&sP[w][j][0];
    a00 = fmaf(p.x, vv.x, a00); a01 = fmaf(p.x, vv.y, a01);
    a10 = fmaf(p.y, vv.x, a10); a11 = fmaf(p.y, vv.y, a11);
    a20 = fmaf(p.z, vv.x, a20); a21 = fmaf(p.z, vv.y, a21);
    a30 = fmaf(p.w, vv.x, a30); a31 = fmaf(p.w, vv.y, a31);
  }

  float* op = out + (s1 * NH + h2 * GG) * DD + lane * 2;
  *(float2*)(op + 0 * DD) = make_float2(a00, a01);
  *(float2*)(op + 1 * DD) = make_float2(a10, a11);
  *(float2*)(op + 2 * DD) = make_float2(a20, a21);
  *(float2*)(op + 3 * DD) = make_float2(a30, a31);
}

extern "C" void kernel_launch(void* const* d_in, const int* in_sizes, int n_in,
                              void* d_out, int out_size, void* d_ws, size_t ws_size,
                              hipStream_t stream) {
  // World (measured): inputs = float32 (harness upcasts fp16), order q,k,v,idx;
  // idx = int32 in [0,8192); output = float32 buffer, np.float32 readback.
  const float* q = (const float*)d_in[0];
  const float* k = (const float*)d_in[1];
  const float* v = (const float*)d_in[2];
  const int* idx = (const int*)d_in[3];
  float* out = (float*)d_out;

  const size_t need = (size_t)2 * KVELTS * sizeof(_Float16);  // 32 MiB
  if (ws_size >= need) {
    _Float16* kh = (_Float16*)d_ws;
    _Float16* vh = kh + KVELTS;
    convert_kv<<<dim3(2048), dim3(256), 0, stream>>>(
        (const float4*)k, (const float4*)v,
        (ushort4*)kh, (ushort4*)vh, KVELTS / 4);
    sparse_attn_f16<<<dim3(2048), dim3(256), 0, stream>>>(q, kh, vh, idx, out);
  } else {
    sparse_attn_f32<<<dim3(2048), dim3(256), 0, stream>>>(q, k, v, idx, out);
  }
}

// Round 5
// 167.802 us; speedup vs baseline: 1.3194x; 1.3194x over previous
//
#include <hip/hip_runtime.h>
#include <stdint.h>
#include <math.h>

#define NH 32
#define NH2 8
#define DD 128
#define KSEL 128
#define GG 4
#define S2MASK 8191   // S2=8192
#define KVELTS (8192 * NH2 * DD)   // 8,388,608 elements per tensor

typedef _Float16 h8   __attribute__((ext_vector_type(8)));
typedef _Float16 h2t  __attribute__((ext_vector_type(2)));
typedef __fp16   hp2  __attribute__((ext_vector_type(2)));
typedef float    f32x4 __attribute__((ext_vector_type(4)));

// exact fp32->fp16 pack (inputs are harness-upcast fp16, so RTZ is lossless)
static __device__ __forceinline__ h8 cvt8(float4 a, float4 b) {
  union { h8 v; hp2 p[4]; } u;
  u.p[0] = __builtin_amdgcn_cvt_pkrtz(a.x, a.y);
  u.p[1] = __builtin_amdgcn_cvt_pkrtz(a.z, a.w);
  u.p[2] = __builtin_amdgcn_cvt_pkrtz(b.x, b.y);
  u.p[3] = __builtin_amdgcn_cvt_pkrtz(b.z, b.w);
  return u.v;
}

// ---- pre-pass: K,V fp32 -> fp16 in workspace (exact; halves gather bytes) ----
__global__ __launch_bounds__(256) void convert_kv(
    const float4* __restrict__ kf, const float4* __restrict__ vf,
    ushort4* __restrict__ kh, ushort4* __restrict__ vh, int n4) {
  int i = blockIdx.x * blockDim.x + threadIdx.x;
  const int stride = gridDim.x * blockDim.x;
  union { ushort4 u; hp2 p[2]; } ua;
  for (; i < n4; i += stride) {
    float4 a = kf[i];
    ua.p[0] = __builtin_amdgcn_cvt_pkrtz(a.x, a.y);
    ua.p[1] = __builtin_amdgcn_cvt_pkrtz(a.z, a.w);
    kh[i] = ua.u;
    float4 b = vf[i];
    ua.p[0] = __builtin_amdgcn_cvt_pkrtz(b.x, b.y);
    ua.p[1] = __builtin_amdgcn_cvt_pkrtz(b.z, b.w);
    vh[i] = ua.u;
  }
}

// ---- main kernel, fp16 K/V from workspace ----
// No s_barrier: all LDS state is wave-private (sOff[w], sP[w]); cross-lane
// visibility within a wave is guaranteed by the in-order DS pipe. Compiler
// fences stop hoisting of sP reads above the writes (R4 empirically correct).
#define WAVE_FENCE() asm volatile("" ::: "memory")

__global__ __launch_bounds__(256) void sparse_attn_f16(
    const float* __restrict__ q, const _Float16* __restrict__ kh,
    const _Float16* __restrict__ vh, const int* __restrict__ idx,
    float* __restrict__ out) {
  __shared__ int sOff[4][KSEL];                      // element offset s2*NH2*DD
  __shared__ __align__(16) float sP[4][KSEL][GG];    // scores -> P, [key][g]

  const int tid = threadIdx.x;
  const int w = tid >> 6;
  const int lane = tid & 63;
  const int h2 = blockIdx.x & 7;                 // XCD-pinned KV head
  const int s1 = ((blockIdx.x >> 3) << 2) + w;   // query position

  const int* ip = idx + (s1 * NH2 + h2) * KSEL;
  sOff[w][lane]      = (ip[lane]      & S2MASK) * (NH2 * DD);
  sOff[w][lane + 64] = (ip[lane + 64] & S2MASK) * (NH2 * DD);

  // MFMA 16x16x32_f16 lane roles:
  //   A: row m = lane&15 (query, m<4 valid, rest zero), k = 8*(lane>>4)+i
  //   B: col    = lane&15 (key-in-tile),                k = 8*(lane>>4)+i
  //   C: col = lane&15 (key), row = 4*(lane>>4)+r -> lanes 0..15 hold all 4 g
  const int m  = lane & 15;
  const int kg = lane >> 4;

  h8 aq[4];
#pragma unroll
  for (int t = 0; t < 4; ++t)
#pragma unroll
    for (int i = 0; i < 8; ++i) aq[t][i] = (_Float16)0;
  if (m < GG) {
    const float* qp = q + (s1 * NH + h2 * GG + m) * DD + kg * 8;
#pragma unroll
    for (int t = 0; t < 4; ++t) {
      float4 f0 = *(const float4*)(qp + 32 * t);
      float4 f1 = *(const float4*)(qp + 32 * t + 4);
      aq[t] = cvt8(f0, f1);
    }
  }

  WAVE_FENCE();

  const float scale = 0.08838834764831845f;  // 1/sqrt(128)

  // ---- Phase 1: scores = Q.K^T via MFMA; fp16 K rows feed B natively ----
#pragma unroll 2
  for (int nt = 0; nt < 8; ++nt) {
    const _Float16* kp = kh + sOff[w][nt * 16 + m] + h2 * DD + kg * 8;
    f32x4 acc = {0.f, 0.f, 0.f, 0.f};
#pragma unroll
    for (int t = 0; t < 4; ++t) {
      h8 bk = *(const h8*)(kp + 32 * t);
      acc = __builtin_amdgcn_mfma_f32_16x16x32_f16(aq[t], bk, acc, 0, 0, 0);
    }
    if (lane < 16) {
      float4 sc = make_float4(acc[0] * scale, acc[1] * scale,
                              acc[2] * scale, acc[3] * scale);
      *(float4*)&sP[w][nt * 16 + lane][0] = sc;
    }
  }

  WAVE_FENCE();

  // ---- Phase 2: softmax, all 64 lanes (lane owns keys {lane, lane+64}) ----
  {
    float4 p0 = *(const float4*)&sP[w][lane][0];
    float4 p1 = *(const float4*)&sP[w][lane + 64][0];
    float4 mx = make_float4(fmaxf(p0.x, p1.x), fmaxf(p0.y, p1.y),
                            fmaxf(p0.z, p1.z), fmaxf(p0.w, p1.w));
#pragma unroll
    for (int off = 1; off < 64; off <<= 1) {
      mx.x = fmaxf(mx.x, __shfl_xor(mx.x, off));
      mx.y = fmaxf(mx.y, __shfl_xor(mx.y, off));
      mx.z = fmaxf(mx.z, __shfl_xor(mx.z, off));
      mx.w = fmaxf(mx.w, __shfl_xor(mx.w, off));
    }
    float4 e0 = make_float4(__expf(p0.x - mx.x), __expf(p0.y - mx.y),
                            __expf(p0.z - mx.z), __expf(p0.w - mx.w));
    float4 e1 = make_float4(__expf(p1.x - mx.x), __expf(p1.y - mx.y),
                            __expf(p1.z - mx.z), __expf(p1.w - mx.w));
    float4 sm = make_float4(e0.x + e1.x, e0.y + e1.y, e0.z + e1.z, e0.w + e1.w);
#pragma unroll
    for (int off = 1; off < 64; off <<= 1) {
      sm.x += __shfl_xor(sm.x, off);
      sm.y += __shfl_xor(sm.y, off);
      sm.z += __shfl_xor(sm.z, off);
      sm.w += __shfl_xor(sm.w, off);
    }
    float4 inv = make_float4(1.f / fmaxf(sm.x, 1e-30f), 1.f / fmaxf(sm.y, 1e-30f),
                             1.f / fmaxf(sm.z, 1e-30f), 1.f / fmaxf(sm.w, 1e-30f));
    *(float4*)&sP[w][lane][0] =
        make_float4(e0.x * inv.x, e0.y * inv.y, e0.z * inv.z, e0.w * inv.w);
    *(float4*)&sP[w][lane + 64][0] =
        make_float4(e1.x * inv.x, e1.y * inv.y, e1.z * inv.z, e1.w * inv.w);
  }

  WAVE_FENCE();

  // ---- Phase 3: O = P . V ; 16-deep load batches, phase-local live ranges ----
  float a00 = 0.f, a01 = 0.f, a10 = 0.f, a11 = 0.f;
  float a20 = 0.f, a21 = 0.f, a30 = 0.f, a31 = 0.f;
  const _Float16* vb = vh + h2 * DD + lane * 2;
#pragma unroll
  for (int ch = 0; ch < 8; ++ch) {
    h2t vv[16];
#pragma unroll
    for (int j = 0; j < 16; ++j)
      vv[j] = *(const h2t*)(vb + sOff[w][ch * 16 + j]);
#pragma unroll
    for (int j = 0; j < 16; ++j) {
      const float4 p = *(const float4*)&sP[w][ch * 16 + j][0];
      const float vx = (float)vv[j][0];
      const float vy = (float)vv[j][1];
      a00 = fmaf(p.x, vx, a00); a01 = fmaf(p.x, vy, a01);
      a10 = fmaf(p.y, vx, a10); a11 = fmaf(p.y, vy, a11);
      a20 = fmaf(p.z, vx, a20); a21 = fmaf(p.z, vy, a21);
      a30 = fmaf(p.w, vx, a30); a31 = fmaf(p.w, vy, a31);
    }
  }

  float* op = out + (s1 * NH + h2 * GG) * DD + lane * 2;
  *(float2*)(op + 0 * DD) = make_float2(a00, a01);
  *(float2*)(op + 1 * DD) = make_float2(a10, a11);
  *(float2*)(op + 2 * DD) = make_float2(a20, a21);
  *(float2*)(op + 3 * DD) = make_float2(a30, a31);
}

// ---- fallback: fp32 K/V direct, used when workspace too small ----
__global__ __launch_bounds__(256) void sparse_attn_f32(
    const float* __restrict__ q, const float* __restrict__ k,
    const float* __restrict__ v, const int* __restrict__ idx,
    float* __restrict__ out) {
  __shared__ int sIdx[4][KSEL];
  __shared__ __align__(16) float sP[4][KSEL][GG];

  const int tid = threadIdx.x;
  const int w = tid >> 6;
  const int lane = tid & 63;
  const int h2 = blockIdx.x & 7;
  const int s1 = ((blockIdx.x >> 3) << 2) + w;

  const int* ip = idx + (s1 * NH2 + h2) * KSEL;
  sIdx[w][lane]      = ip[lane] & S2MASK;
  sIdx[w][lane + 64] = ip[lane + 64] & S2MASK;

  const int m  = lane & 15;
  const int kg = lane >> 4;

  h8 aq[4];
#pragma unroll
  for (int t = 0; t < 4; ++t)
#pragma unroll
    for (int i = 0; i < 8; ++i) aq[t][i] = (_Float16)0;
  if (m < GG) {
    const float* qp = q + (s1 * NH + h2 * GG + m) * DD + kg * 8;
#pragma unroll
    for (int t = 0; t < 4; ++t) {
      float4 f0 = *(const float4*)(qp + 32 * t);
      float4 f1 = *(const float4*)(qp + 32 * t + 4);
      aq[t] = cvt8(f0, f1);
    }
  }
  __syncthreads();

  const float scale = 0.08838834764831845f;
#pragma unroll 2
  for (int nt = 0; nt < 8; ++nt) {
    const int s2 = sIdx[w][nt * 16 + m];
    const float* kp = k + (s2 * NH2 + h2) * DD + kg * 8;
    f32x4 acc = {0.f, 0.f, 0.f, 0.f};
#pragma unroll
    for (int t = 0; t < 4; ++t) {
      float4 f0 = *(const float4*)(kp + 32 * t);
      float4 f1 = *(const float4*)(kp + 32 * t + 4);
      acc = __builtin_amdgcn_mfma_f32_16x16x32_f16(aq[t], cvt8(f0, f1), acc, 0, 0, 0);
    }
    if (lane < 16) {
      float4 sc = make_float4(acc[0] * scale, acc[1] * scale,
                              acc[2] * scale, acc[3] * scale);
      *(float4*)&sP[w][nt * 16 + lane][0] = sc;
    }
  }
  __syncthreads();

  {
    float4 p0 = *(const float4*)&sP[w][lane][0];
    float4 p1 = *(const float4*)&sP[w][lane + 64][0];
    float4 mx = make_float4(fmaxf(p0.x, p1.x), fmaxf(p0.y, p1.y),
                            fmaxf(p0.z, p1.z), fmaxf(p0.w, p1.w));
#pragma unroll
    for (int off = 1; off < 64; off <<= 1) {
      mx.x = fmaxf(mx.x, __shfl_xor(mx.x, off));
      mx.y = fmaxf(mx.y, __shfl_xor(mx.y, off));
      mx.z = fmaxf(mx.z, __shfl_xor(mx.z, off));
      mx.w = fmaxf(mx.w, __shfl_xor(mx.w, off));
    }
    float4 e0 = make_float4(__expf(p0.x - mx.x), __expf(p0.y - mx.y),
                            __expf(p0.z - mx.z), __expf(p0.w - mx.w));
    float4 e1 = make_float4(__expf(p1.x - mx.x), __expf(p1.y - mx.y),
                            __expf(p1.z - mx.z), __expf(p1.w - mx.w));
    float4 sm = make_float4(e0.x + e1.x, e0.y + e1.y, e0.z + e1.z, e0.w + e1.w);
#pragma unroll
    for (int off = 1; off < 64; off <<= 1) {
      sm.x += __shfl_xor(sm.x, off);
      sm.y += __shfl_xor(sm.y, off);
      sm.z += __shfl_xor(sm.z, off);
      sm.w += __shfl_xor(sm.w, off);
    }
    float4 inv = make_float4(1.f / fmaxf(sm.x, 1e-30f), 1.f / fmaxf(sm.y, 1e-30f),
                             1.f / fmaxf(sm.z, 1e-30f), 1.f / fmaxf(sm.w, 1e-30f));
    *(float4*)&sP[w][lane][0] =
        make_float4(e0.x * inv.x, e0.y * inv.y, e0.z * inv.z, e0.w * inv.w);
    *(float4*)&sP[w][lane + 64][0] =
        make_float4(e1.x * inv.x, e1.y * inv.y, e1.z * inv.z, e1.w * inv.w);
  }
  __syncthreads();

  float a00 = 0.f, a01 = 0.f, a10 = 0.f, a11 = 0.f;
  float a20 = 0.f, a21 = 0.f, a30 = 0.f, a31 = 0.f;
  const float* vb = v + h2 * DD + lane * 2;
#pragma unroll 8
  for (int j = 0; j < KSEL; ++j) {
    const int s2 = sIdx[w][j];
    const float2 vv = *(const float2*)(vb + (size_t)s2 * (NH2 * DD));
    const float4 p = *(const float4*)&sP[w][j][0];
    a00 = fmaf(p.x, vv.x, a00); a01 = fmaf(p.x, vv.y, a01);
    a10 = fmaf(p.y, vv.x, a10); a11 = fmaf(p.y, vv.y, a11);
    a20 = fmaf(p.z, vv.x, a20); a21 = fmaf(p.z, vv.y, a21);
    a30 = fmaf(p.w, vv.x, a30); a31 = fmaf(p.w, vv.y, a31);
  }

  float* op = out + (s1 * NH + h2 * GG) * DD + lane * 2;
  *(float2*)(op + 0 * DD) = make_float2(a00, a01);
  *(float2*)(op + 1 * DD) = make_float2(a10, a11);
  *(float2*)(op + 2 * DD) = make_float2(a20, a21);
  *(float2*)(op + 3 * DD) = make_float2(a30, a31);
}

extern "C" void kernel_launch(void* const* d_in, const int* in_sizes, int n_in,
                              void* d_out, int out_size, void* d_ws, size_t ws_size,
                              hipStream_t stream) {
  // World (measured): inputs = float32 (harness upcasts fp16), order q,k,v,idx;
  // idx = int32 in [0,8192); output = float32 buffer, np.float32 readback.
  const float* q = (const float*)d_in[0];
  const float* k = (const float*)d_in[1];
  const float* v = (const float*)d_in[2];
  const int* idx = (const int*)d_in[3];
  float* out = (float*)d_out;

  const size_t need = (size_t)2 * KVELTS * sizeof(_Float16);  // 32 MiB
  if (ws_size >= need) {
    _Float16* kh = (_Float16*)d_ws;
    _Float16* vh = kh + KVELTS;
    convert_kv<<<dim3(2048), dim3(256), 0, stream>>>(
        (const float4*)k, (const float4*)v,
        (ushort4*)kh, (ushort4*)vh, KVELTS / 4);
    sparse_attn_f16<<<dim3(2048), dim3(256), 0, stream>>>(q, kh, vh, idx, out);
  } else {
    sparse_attn_f32<<<dim3(2048), dim3(256), 0, stream>>>(q, k, v, idx, out);
  }
}

// Round 6
// 166.824 us; speedup vs baseline: 1.3272x; 1.0059x over previous
//
#include <hip/hip_runtime.h>
#include <stdint.h>
#include <math.h>

#define NH 32
#define NH2 8
#define DD 128
#define KSEL 128
#define GG 4
#define S2MASK 8191   // S2=8192
#define KVELTS (8192 * NH2 * DD)   // 8,388,608 elements per tensor

typedef _Float16 h8   __attribute__((ext_vector_type(8)));
typedef _Float16 h2t  __attribute__((ext_vector_type(2)));
typedef __fp16   hp2  __attribute__((ext_vector_type(2)));
typedef float    f32x4 __attribute__((ext_vector_type(4)));

// exact fp32->fp16 pack (inputs are harness-upcast fp16, so RTZ is lossless)
static __device__ __forceinline__ h8 cvt8(float4 a, float4 b) {
  union { h8 v; hp2 p[4]; } u;
  u.p[0] = __builtin_amdgcn_cvt_pkrtz(a.x, a.y);
  u.p[1] = __builtin_amdgcn_cvt_pkrtz(a.z, a.w);
  u.p[2] = __builtin_amdgcn_cvt_pkrtz(b.x, b.y);
  u.p[3] = __builtin_amdgcn_cvt_pkrtz(b.z, b.w);
  return u.v;
}

// ---- pre-pass: K,V fp32 -> fp16, h2-AFFINE ----
// Same grid shape (2048x256) and same blockIdx&7 -> h2 mapping as the attn
// kernel, so each XCD's L2 is left holding exactly its own h2 slice
// (2 MB K + 2 MB V fp16 = 4 MB = one XCD L2). Attn's gathers then hit the
// local L2 instead of cold-missing to L3/HBM (R5 FETCH showed a full-KV
// cold-miss storm: 36 MB/dispatch).
__global__ __launch_bounds__(256) void convert_kv_affine(
    const float4* __restrict__ kf, const float4* __restrict__ vf,
    ushort* __restrict__ kh, ushort* __restrict__ vh) {
  const int h2 = blockIdx.x & 7;
  const int chunk = blockIdx.x >> 3;          // 0..255, 32 s2-rows each
  const int tid = threadIdx.x;
  union { ushort4 u; hp2 p[2]; } ua;
#pragma unroll
  for (int it = 0; it < 4; ++it) {
    const int i = it * 256 + tid;             // 0..1023
    const int s2r = i >> 5;                   // row 0..31
    const int c4 = i & 31;                    // float4-chunk in row
    const int e4 = ((chunk * 32 + s2r) * NH2 + h2) * (DD / 4) + c4;
    {
      float4 a = kf[e4];
      ua.p[0] = __builtin_amdgcn_cvt_pkrtz(a.x, a.y);
      ua.p[1] = __builtin_amdgcn_cvt_pkrtz(a.z, a.w);
      *(ushort4*)(kh + e4 * 4) = ua.u;
    }
    {
      float4 b = vf[e4];
      ua.p[0] = __builtin_amdgcn_cvt_pkrtz(b.x, b.y);
      ua.p[1] = __builtin_amdgcn_cvt_pkrtz(b.z, b.w);
      *(ushort4*)(vh + e4 * 4) = ua.u;
    }
  }
}

// ---- main kernel, fp16 K/V from workspace (unchanged from R5) ----
// No s_barrier: all LDS state is wave-private (sOff[w], sP[w]); cross-lane
// visibility within a wave is guaranteed by the in-order DS pipe.
#define WAVE_FENCE() asm volatile("" ::: "memory")

__global__ __launch_bounds__(256) void sparse_attn_f16(
    const float* __restrict__ q, const _Float16* __restrict__ kh,
    const _Float16* __restrict__ vh, const int* __restrict__ idx,
    float* __restrict__ out) {
  __shared__ int sOff[4][KSEL];                      // element offset s2*NH2*DD
  __shared__ __align__(16) float sP[4][KSEL][GG];    // scores -> P, [key][g]

  const int tid = threadIdx.x;
  const int w = tid >> 6;
  const int lane = tid & 63;
  const int h2 = blockIdx.x & 7;                 // XCD-pinned KV head
  const int s1 = ((blockIdx.x >> 3) << 2) + w;   // query position

  const int* ip = idx + (s1 * NH2 + h2) * KSEL;
  sOff[w][lane]      = (ip[lane]      & S2MASK) * (NH2 * DD);
  sOff[w][lane + 64] = (ip[lane + 64] & S2MASK) * (NH2 * DD);

  // MFMA 16x16x32_f16 lane roles:
  //   A: row m = lane&15 (query, m<4 valid, rest zero), k = 8*(lane>>4)+i
  //   B: col    = lane&15 (key-in-tile),                k = 8*(lane>>4)+i
  //   C: col = lane&15 (key), row = 4*(lane>>4)+r -> lanes 0..15 hold all 4 g
  const int m  = lane & 15;
  const int kg = lane >> 4;

  h8 aq[4];
#pragma unroll
  for (int t = 0; t < 4; ++t)
#pragma unroll
    for (int i = 0; i < 8; ++i) aq[t][i] = (_Float16)0;
  if (m < GG) {
    const float* qp = q + (s1 * NH + h2 * GG + m) * DD + kg * 8;
#pragma unroll
    for (int t = 0; t < 4; ++t) {
      float4 f0 = *(const float4*)(qp + 32 * t);
      float4 f1 = *(const float4*)(qp + 32 * t + 4);
      aq[t] = cvt8(f0, f1);
    }
  }

  WAVE_FENCE();

  const float scale = 0.08838834764831845f;  // 1/sqrt(128)

  // ---- Phase 1: scores = Q.K^T via MFMA; fp16 K rows feed B natively ----
#pragma unroll 2
  for (int nt = 0; nt < 8; ++nt) {
    const _Float16* kp = kh + sOff[w][nt * 16 + m] + h2 * DD + kg * 8;
    f32x4 acc = {0.f, 0.f, 0.f, 0.f};
#pragma unroll
    for (int t = 0; t < 4; ++t) {
      h8 bk = *(const h8*)(kp + 32 * t);
      acc = __builtin_amdgcn_mfma_f32_16x16x32_f16(aq[t], bk, acc, 0, 0, 0);
    }
    if (lane < 16) {
      float4 sc = make_float4(acc[0] * scale, acc[1] * scale,
                              acc[2] * scale, acc[3] * scale);
      *(float4*)&sP[w][nt * 16 + lane][0] = sc;
    }
  }

  WAVE_FENCE();

  // ---- Phase 2: softmax, all 64 lanes (lane owns keys {lane, lane+64}) ----
  {
    float4 p0 = *(const float4*)&sP[w][lane][0];
    float4 p1 = *(const float4*)&sP[w][lane + 64][0];
    float4 mx = make_float4(fmaxf(p0.x, p1.x), fmaxf(p0.y, p1.y),
                            fmaxf(p0.z, p1.z), fmaxf(p0.w, p1.w));
#pragma unroll
    for (int off = 1; off < 64; off <<= 1) {
      mx.x = fmaxf(mx.x, __shfl_xor(mx.x, off));
      mx.y = fmaxf(mx.y, __shfl_xor(mx.y, off));
      mx.z = fmaxf(mx.z, __shfl_xor(mx.z, off));
      mx.w = fmaxf(mx.w, __shfl_xor(mx.w, off));
    }
    float4 e0 = make_float4(__expf(p0.x - mx.x), __expf(p0.y - mx.y),
                            __expf(p0.z - mx.z), __expf(p0.w - mx.w));
    float4 e1 = make_float4(__expf(p1.x - mx.x), __expf(p1.y - mx.y),
                            __expf(p1.z - mx.z), __expf(p1.w - mx.w));
    float4 sm = make_float4(e0.x + e1.x, e0.y + e1.y, e0.z + e1.z, e0.w + e1.w);
#pragma unroll
    for (int off = 1; off < 64; off <<= 1) {
      sm.x += __shfl_xor(sm.x, off);
      sm.y += __shfl_xor(sm.y, off);
      sm.z += __shfl_xor(sm.z, off);
      sm.w += __shfl_xor(sm.w, off);
    }
    float4 inv = make_float4(1.f / fmaxf(sm.x, 1e-30f), 1.f / fmaxf(sm.y, 1e-30f),
                             1.f / fmaxf(sm.z, 1e-30f), 1.f / fmaxf(sm.w, 1e-30f));
    *(float4*)&sP[w][lane][0] =
        make_float4(e0.x * inv.x, e0.y * inv.y, e0.z * inv.z, e0.w * inv.w);
    *(float4*)&sP[w][lane + 64][0] =
        make_float4(e1.x * inv.x, e1.y * inv.y, e1.z * inv.z, e1.w * inv.w);
  }

  WAVE_FENCE();

  // ---- Phase 3: O = P . V ; 16-deep load batches, phase-local live ranges ----
  float a00 = 0.f, a01 = 0.f, a10 = 0.f, a11 = 0.f;
  float a20 = 0.f, a21 = 0.f, a30 = 0.f, a31 = 0.f;
  const _Float16* vb = vh + h2 * DD + lane * 2;
#pragma unroll
  for (int ch = 0; ch < 8; ++ch) {
    h2t vv[16];
#pragma unroll
    for (int j = 0; j < 16; ++j)
      vv[j] = *(const h2t*)(vb + sOff[w][ch * 16 + j]);
#pragma unroll
    for (int j = 0; j < 16; ++j) {
      const float4 p = *(const float4*)&sP[w][ch * 16 + j][0];
      const float vx = (float)vv[j][0];
      const float vy = (float)vv[j][1];
      a00 = fmaf(p.x, vx, a00); a01 = fmaf(p.x, vy, a01);
      a10 = fmaf(p.y, vx, a10); a11 = fmaf(p.y, vy, a11);
      a20 = fmaf(p.z, vx, a20); a21 = fmaf(p.z, vy, a21);
      a30 = fmaf(p.w, vx, a30); a31 = fmaf(p.w, vy, a31);
    }
  }

  float* op = out + (s1 * NH + h2 * GG) * DD + lane * 2;
  *(float2*)(op + 0 * DD) = make_float2(a00, a01);
  *(float2*)(op + 1 * DD) = make_float2(a10, a11);
  *(float2*)(op + 2 * DD) = make_float2(a20, a21);
  *(float2*)(op + 3 * DD) = make_float2(a30, a31);
}

// ---- fallback: fp32 K/V direct, used when workspace too small ----
__global__ __launch_bounds__(256) void sparse_attn_f32(
    const float* __restrict__ q, const float* __restrict__ k,
    const float* __restrict__ v, const int* __restrict__ idx,
    float* __restrict__ out) {
  __shared__ int sIdx[4][KSEL];
  __shared__ __align__(16) float sP[4][KSEL][GG];

  const int tid = threadIdx.x;
  const int w = tid >> 6;
  const int lane = tid & 63;
  const int h2 = blockIdx.x & 7;
  const int s1 = ((blockIdx.x >> 3) << 2) + w;

  const int* ip = idx + (s1 * NH2 + h2) * KSEL;
  sIdx[w][lane]      = ip[lane] & S2MASK;
  sIdx[w][lane + 64] = ip[lane + 64] & S2MASK;

  const int m  = lane & 15;
  const int kg = lane >> 4;

  h8 aq[4];
#pragma unroll
  for (int t = 0; t < 4; ++t)
#pragma unroll
    for (int i = 0; i < 8; ++i) aq[t][i] = (_Float16)0;
  if (m < GG) {
    const float* qp = q + (s1 * NH + h2 * GG + m) * DD + kg * 8;
#pragma unroll
    for (int t = 0; t < 4; ++t) {
      float4 f0 = *(const float4*)(qp + 32 * t);
      float4 f1 = *(const float4*)(qp + 32 * t + 4);
      aq[t] = cvt8(f0, f1);
    }
  }
  __syncthreads();

  const float scale = 0.08838834764831845f;
#pragma unroll 2
  for (int nt = 0; nt < 8; ++nt) {
    const int s2 = sIdx[w][nt * 16 + m];
    const float* kp = k + (s2 * NH2 + h2) * DD + kg * 8;
    f32x4 acc = {0.f, 0.f, 0.f, 0.f};
#pragma unroll
    for (int t = 0; t < 4; ++t) {
      float4 f0 = *(const float4*)(kp + 32 * t);
      float4 f1 = *(const float4*)(kp + 32 * t + 4);
      acc = __builtin_amdgcn_mfma_f32_16x16x32_f16(aq[t], cvt8(f0, f1), acc, 0, 0, 0);
    }
    if (lane < 16) {
      float4 sc = make_float4(acc[0] * scale, acc[1] * scale,
                              acc[2] * scale, acc[3] * scale);
      *(float4*)&sP[w][nt * 16 + lane][0] = sc;
    }
  }
  __syncthreads();

  {
    float4 p0 = *(const float4*)&sP[w][lane][0];
    float4 p1 = *(const float4*)&sP[w][lane + 64][0];
    float4 mx = make_float4(fmaxf(p0.x, p1.x), fmaxf(p0.y, p1.y),
                            fmaxf(p0.z, p1.z), fmaxf(p0.w, p1.w));
#pragma unroll
    for (int off = 1; off < 64; off <<= 1) {
      mx.x = fmaxf(mx.x, __shfl_xor(mx.x, off));
      mx.y = fmaxf(mx.y, __shfl_xor(mx.y, off));
      mx.z = fmaxf(mx.z, __shfl_xor(mx.z, off));
      mx.w = fmaxf(mx.w, __shfl_xor(mx.w, off));
    }
    float4 e0 = make_float4(__expf(p0.x - mx.x), __expf(p0.y - mx.y),
                            __expf(p0.z - mx.z), __expf(p0.w - mx.w));
    float4 e1 = make_float4(__expf(p1.x - mx.x), __expf(p1.y - mx.y),
                            __expf(p1.z - mx.z), __expf(p1.w - mx.w));
    float4 sm = make_float4(e0.x + e1.x, e0.y + e1.y, e0.z + e1.z, e0.w + e1.w);
#pragma unroll
    for (int off = 1; off < 64; off <<= 1) {
      sm.x += __shfl_xor(sm.x, off);
      sm.y += __shfl_xor(sm.y, off);
      sm.z += __shfl_xor(sm.z, off);
      sm.w += __shfl_xor(sm.w, off);
    }
    float4 inv = make_float4(1.f / fmaxf(sm.x, 1e-30f), 1.f / fmaxf(sm.y, 1e-30f),
                             1.f / fmaxf(sm.z, 1e-30f), 1.f / fmaxf(sm.w, 1e-30f));
    *(float4*)&sP[w][lane][0] =
        make_float4(e0.x * inv.x, e0.y * inv.y, e0.z * inv.z, e0.w * inv.w);
    *(float4*)&sP[w][lane + 64][0] =
        make_float4(e1.x * inv.x, e1.y * inv.y, e1.z * inv.z, e1.w * inv.w);
  }
  __syncthreads();

  float a00 = 0.f, a01 = 0.f, a10 = 0.f, a11 = 0.f;
  float a20 = 0.f, a21 = 0.f, a30 = 0.f, a31 = 0.f;
  const float* vb = v + h2 * DD + lane * 2;
#pragma unroll 8
  for (int j = 0; j < KSEL; ++j) {
    const int s2 = sIdx[w][j];
    const float2 vv = *(const float2*)(vb + (size_t)s2 * (NH2 * DD));
    const float4 p = *(const float4*)&sP[w][j][0];
    a00 = fmaf(p.x, vv.x, a00); a01 = fmaf(p.x, vv.y, a01);
    a10 = fmaf(p.y, vv.x, a10); a11 = fmaf(p.y, vv.y, a11);
    a20 = fmaf(p.z, vv.x, a20); a21 = fmaf(p.z, vv.y, a21);
    a30 = fmaf(p.w, vv.x, a30); a31 = fmaf(p.w, vv.y, a31);
  }

  float* op = out + (s1 * NH + h2 * GG) * DD + lane * 2;
  *(float2*)(op + 0 * DD) = make_float2(a00, a01);
  *(float2*)(op + 1 * DD) = make_float2(a10, a11);
  *(float2*)(op + 2 * DD) = make_float2(a20, a21);
  *(float2*)(op + 3 * DD) = make_float2(a30, a31);
}

extern "C" void kernel_launch(void* const* d_in, const int* in_sizes, int n_in,
                              void* d_out, int out_size, void* d_ws, size_t ws_size,
                              hipStream_t stream) {
  // World (measured): inputs = float32 (harness upcasts fp16), order q,k,v,idx;
  // idx = int32 in [0,8192); output = float32 buffer, np.float32 readback.
  const float* q = (const float*)d_in[0];
  const float* k = (const float*)d_in[1];
  const float* v = (const float*)d_in[2];
  const int* idx = (const int*)d_in[3];
  float* out = (float*)d_out;

  const size_t need = (size_t)2 * KVELTS * sizeof(_Float16);  // 32 MiB
  if (ws_size >= need) {
    _Float16* kh = (_Float16*)d_ws;
    _Float16* vh = kh + KVELTS;
    convert_kv_affine<<<dim3(2048), dim3(256), 0, stream>>>(
        (const float4*)k, (const float4*)v,
        (ushort*)kh, (ushort*)vh);
    sparse_attn_f16<<<dim3(2048), dim3(256), 0, stream>>>(q, kh, vh, idx, out);
  } else {
    sparse_attn_f32<<<dim3(2048), dim3(256), 0, stream>>>(q, k, v, idx, out);
  }
}